// Round 6
// baseline (2206.518 us; speedup 1.0000x reference)
//
#include <hip/hip_runtime.h>

// PolicyAwareLSTM: 2-layer LSTM (4096 x 336, 32->64->32) + seq1-MHA (== two 32x32
// matmuls) + dense 32->64->24 head. fp32 throughout (no fp32 MFMA on CDNA4).
//
// R6 = R5 resubmitted verbatim (R5 bench died in infra: "container failed twice";
// no counters returned, kernel re-audited clean -- races/OOB/divergent-barrier none).
//
// R5 theory: DS-pipe is the limiter (R4 count: ~1312 wave-level LDS instr/CU-step
// ~= 12-13K cy vs 14.4K measured period; VALUBusy 70% is overlap, not the limit).
// Per-thread act ingest (96 floats/step = 24 b128) is fixed, so raise the
// FMA-per-ingest ratio by halving NT to 256: per-thread weights 72 -> 144
// floats (whole weight set still held exactly once per block). Each thread owns
// a UNIT PAIR: L1 {u, u+32}, L2 {u, u+16} -- pair split across column halves so
// zp partial writes stay stride-16B conflict-free. DS instr/CU-step ~930 (-30%).
// launch_bounds(256,2) -> 256-VGPR budget (est ~200 live), 512 blocks,
// 2 blocks/CU = 8 waves/CU. FP association per output identical to R4.

#define B_TOTAL 4096
#define T_STEPS 336
#define NF      32     // input features
#define U1N     64     // layer-1 units
#define G1      256    // 4*U1N
#define U2N     32     // layer-2 units
#define G2      128    // 4*U2N
#define RROWS   8      // batch rows per block
#define NT      256    // threads per block
#define KH1     12     // L1 K-slice (8 k-groups x 12 = 96)
#define KG1     8
#define KH2     6      // L2 K-slice (16 k-groups x 6 = 96)
#define KG2     16

__device__ __forceinline__ float fast_sigmoid(float x) {
    return __fdividef(1.0f, 1.0f + __expf(-x));
}

__device__ __forceinline__ float fast_tanh(float x) {
    float ax = fabsf(x);
    float e  = __expf(-2.0f * ax);
    float r  = __fdividef(1.0f - e, 1.0f + e);
    return __builtin_copysignf(r, x);
}

__global__ __launch_bounds__(NT, 2) void lstm_fused(
    const float* __restrict__ x,
    const float* __restrict__ W1, const float* __restrict__ U1, const float* __restrict__ b1,
    const float* __restrict__ W2, const float* __restrict__ U2, const float* __restrict__ b2,
    const float* __restrict__ Wv, const float* __restrict__ bv,
    const float* __restrict__ Wo, const float* __restrict__ bo,
    const float* __restrict__ Wd1, const float* __restrict__ bd1,
    const float* __restrict__ Wd2, const float* __restrict__ bd2,
    float* __restrict__ out)
{
    __shared__ float act_sh[RROWS][128];       // [x(32) | h1(64) | h2(32)] per row, 4KB
    __shared__ float zp[RROWS * KG1 * G1];     // 64KB: L1/L2 partials (flat); head scratch

    const int tid = threadIdx.x;
    const int r0  = blockIdx.x * RROWS;

    // ---- thread roles
    const int kg1 = tid >> 5;                  // L1 k-group (0..7) -- wave-ish uniform
    const int up1 = tid & 31;                  // L1 unit pair {up1, up1+32}
    const int kg2 = tid >> 4;                  // L2 k-group (0..15)
    const int up2 = tid & 15;                  // L2 unit pair {up2, up2+16}
    const int pr  = tid >> 5, pu = tid & 31;   // (row,unit) single mapping: gates, park, head

    // ---- L1 weights: 4 gate-columns of two units, K-sliced
    float4 w1a[KH1], w1b[KH1];
    #pragma unroll
    for (int j = 0; j < KH1; ++j) {
        const int kk = KH1 * kg1 + j;          // 0..95 over [x(32)|h1(64)]
        const float* row = (kk < NF) ? (W1 + kk * G1) : (U1 + (kk - NF) * G1);
        w1a[j] = make_float4(row[up1],      row[64 + up1],  row[128 + up1], row[192 + up1]);
        w1b[j] = make_float4(row[32 + up1], row[96 + up1],  row[160 + up1], row[224 + up1]);
    }
    float4 b1a = make_float4(0.f, 0.f, 0.f, 0.f);
    float4 b1b = make_float4(0.f, 0.f, 0.f, 0.f);
    if (kg1 == 0) {
        b1a = make_float4(b1[up1],      b1[64 + up1], b1[128 + up1], b1[192 + up1]);
        b1b = make_float4(b1[32 + up1], b1[96 + up1], b1[160 + up1], b1[224 + up1]);
    }

    // ---- L2 weights
    float4 w2a[KH2], w2b[KH2];
    #pragma unroll
    for (int j = 0; j < KH2; ++j) {
        const int kk = KH2 * kg2 + j;          // 0..95 over [h1(64)|h2(32)]
        const float* row = (kk < U1N) ? (W2 + kk * G2) : (U2 + (kk - U1N) * G2);
        w2a[j] = make_float4(row[up2],      row[32 + up2], row[64 + up2],  row[96 + up2]);
        w2b[j] = make_float4(row[16 + up2], row[48 + up2], row[80 + up2],  row[112 + up2]);
    }
    float4 b2a = make_float4(0.f, 0.f, 0.f, 0.f);
    float4 b2b = make_float4(0.f, 0.f, 0.f, 0.f);
    if (kg2 == 0) {
        b2a = make_float4(b2[up2],      b2[32 + up2], b2[64 + up2], b2[96 + up2]);
        b2b = make_float4(b2[16 + up2], b2[48 + up2], b2[80 + up2], b2[112 + up2]);
    }

    // ---- init: zero act, zero cell states
    reinterpret_cast<float4*>(&act_sh[0][0])[tid] = make_float4(0.f, 0.f, 0.f, 0.f); // 1024 floats
    float c1a = 0.f, c1b = 0.f, c2 = 0.f;

    const int xbase = (r0 + pr) * (T_STEPS * NF) + pu;     // x-park: row pr, feat pu
    __syncthreads();
    act_sh[pr][pu] = x[xbase];                             // x_0
    __syncthreads();

    for (int t = 0; t < T_STEPS; ++t) {
        // prefetch next step's x slice (parked after B1)
        const int tn = (t + 1 < T_STEPS) ? (t + 1) : (T_STEPS - 1);
        const float xnext = x[xbase + tn * NF];

        // ---- phase 1: z1 partials for units {up1, up1+32}, k in [12*kg1, +12)
        {
            const int ab = KH1 * kg1;          // 48B multiples -> 16B aligned
            #pragma unroll
            for (int r = 0; r < RROWS; ++r) {
                const float4* av = reinterpret_cast<const float4*>(&act_sh[r][ab]);
                const float4 a0 = av[0], a1 = av[1], a2 = av[2];
                float a[KH1];
                a[0]=a0.x; a[1]=a0.y; a[2]=a0.z;  a[3]=a0.w;
                a[4]=a1.x; a[5]=a1.y; a[6]=a1.z;  a[7]=a1.w;
                a[8]=a2.x; a[9]=a2.y; a[10]=a2.z; a[11]=a2.w;
                float4 accA = b1a, accB = b1b;
                #pragma unroll
                for (int j = 0; j < KH1; ++j) {
                    accA.x = fmaf(a[j], w1a[j].x, accA.x);
                    accA.y = fmaf(a[j], w1a[j].y, accA.y);
                    accA.z = fmaf(a[j], w1a[j].z, accA.z);
                    accA.w = fmaf(a[j], w1a[j].w, accA.w);
                    accB.x = fmaf(a[j], w1b[j].x, accB.x);
                    accB.y = fmaf(a[j], w1b[j].y, accB.y);
                    accB.z = fmaf(a[j], w1b[j].z, accB.z);
                    accB.w = fmaf(a[j], w1b[j].w, accB.w);
                }
                float* zb = &zp[(r * KG1 + kg1) * G1];
                *reinterpret_cast<float4*>(&zb[4 * up1])       = accA;  // cols of units 0..31
                *reinterpret_cast<float4*>(&zb[128 + 4 * up1]) = accB;  // cols of units 32..63
            }
        }
        __syncthreads();  // B1: zp(L1) ready; act reads of phase1 done

        // ---- gate 1: thread = (row pr, units pu & pu+32); sum 8 k-group partials
        {
            float4 zA = make_float4(0.f, 0.f, 0.f, 0.f);
            float4 zB = make_float4(0.f, 0.f, 0.f, 0.f);
            #pragma unroll
            for (int k = 0; k < KG1; ++k) {
                const float* zb = &zp[(pr * KG1 + k) * G1];
                const float4 pa = *reinterpret_cast<const float4*>(&zb[4 * pu]);
                const float4 pb = *reinterpret_cast<const float4*>(&zb[128 + 4 * pu]);
                zA.x += pa.x; zA.y += pa.y; zA.z += pa.z; zA.w += pa.w;
                zB.x += pb.x; zB.y += pb.y; zB.z += pb.z; zB.w += pb.w;
            }
            {
                const float ig = fast_sigmoid(zA.x);
                const float fg = fast_sigmoid(zA.y);
                const float gg = fast_tanh(zA.z);
                const float og = fast_sigmoid(zA.w);
                c1a = fmaf(fg, c1a, ig * gg);
                act_sh[pr][NF + pu] = og * fast_tanh(c1a);        // h1[pu]
            }
            {
                const float ig = fast_sigmoid(zB.x);
                const float fg = fast_sigmoid(zB.y);
                const float gg = fast_tanh(zB.z);
                const float og = fast_sigmoid(zB.w);
                c1b = fmaf(fg, c1b, ig * gg);
                act_sh[pr][NF + 32 + pu] = og * fast_tanh(c1b);   // h1[pu+32]
            }
            act_sh[pr][pu] = xnext;                               // park x_{t+1}
        }
        __syncthreads();  // B2: h1_t + x_{t+1} visible; zp(L1) reads done

        // ---- phase 2: z2 partials for units {up2, up2+16}, k in act-coords [32+6*kg2, +6)
        {
            const int ab2 = NF + KH2 * kg2;    // 8B aligned
            #pragma unroll
            for (int r = 0; r < RROWS; ++r) {
                const float2* av = reinterpret_cast<const float2*>(&act_sh[r][ab2]);
                const float2 a0 = av[0], a1 = av[1], a2 = av[2];
                float a[KH2];
                a[0]=a0.x; a[1]=a0.y; a[2]=a1.x; a[3]=a1.y; a[4]=a2.x; a[5]=a2.y;
                float4 accA = b2a, accB = b2b;
                #pragma unroll
                for (int j = 0; j < KH2; ++j) {
                    accA.x = fmaf(a[j], w2a[j].x, accA.x);
                    accA.y = fmaf(a[j], w2a[j].y, accA.y);
                    accA.z = fmaf(a[j], w2a[j].z, accA.z);
                    accA.w = fmaf(a[j], w2a[j].w, accA.w);
                    accB.x = fmaf(a[j], w2b[j].x, accB.x);
                    accB.y = fmaf(a[j], w2b[j].y, accB.y);
                    accB.z = fmaf(a[j], w2b[j].z, accB.z);
                    accB.w = fmaf(a[j], w2b[j].w, accB.w);
                }
                float* zb = &zp[(r * KG2 + kg2) * G2];
                *reinterpret_cast<float4*>(&zb[4 * up2])      = accA;  // cols of units 0..15
                *reinterpret_cast<float4*>(&zb[64 + 4 * up2]) = accB;  // cols of units 16..31
            }
        }
        __syncthreads();  // B3: zp(L2) ready; act reads of phase2 done

        // ---- gate 2: thread = (row pr, unit pu); sum 16 k-group partials
        {
            float4 z = make_float4(0.f, 0.f, 0.f, 0.f);
            #pragma unroll
            for (int k = 0; k < KG2; ++k) {
                const float4 p = *reinterpret_cast<const float4*>(&zp[(pr * KG2 + k) * G2 + 4 * pu]);
                z.x += p.x; z.y += p.y; z.z += p.z; z.w += p.w;
            }
            const float ig = fast_sigmoid(z.x);
            const float fg = fast_sigmoid(z.y);
            const float gg = fast_tanh(z.z);
            const float og = fast_sigmoid(z.w);
            c2 = fmaf(fg, c2, ig * gg);
            act_sh[pr][96 + pu] = og * fast_tanh(c2);             // h2_t
        }
        __syncthreads();  // B4: zp free for next phase1; h2_t visible
    }

    // ---- head: v = h2@Wv+bv ; o = v@Wo+bo ; d1 = relu(o@Wd1+bd1) ; out = d1@Wd2+bd2
    {
        float* hb = &zp[0];                    // scratch: v[0..256), o[256..512), d1[512..1024)
        {
            float acc = bv[pu];
            #pragma unroll
            for (int j = 0; j < 32; ++j) acc = fmaf(act_sh[pr][96 + j], Wv[j * 32 + pu], acc);
            hb[tid] = acc;                     // v[r][u]
        }
        __syncthreads();
        {
            float acc = bo[pu];
            #pragma unroll
            for (int j = 0; j < 32; ++j) acc = fmaf(hb[pr * 32 + j], Wo[j * 32 + pu], acc);
            hb[256 + tid] = acc;               // o[r][u] (separate region; no hazard)
        }
        __syncthreads();
        #pragma unroll
        for (int kk = 0; kk < 2; ++kk) {
            const int c64 = pu + 32 * kk;      // d1: 2 cols per thread
            float acc = bd1[c64];
            #pragma unroll
            for (int j = 0; j < 32; ++j) acc = fmaf(hb[256 + pr * 32 + j], Wd1[j * 64 + c64], acc);
            hb[512 + pr * 64 + c64] = fmaxf(acc, 0.f);
        }
        __syncthreads();
        if (tid < RROWS * 24) {
            const int rr = tid / 24, cc = tid - rr * 24;
            float acc = bd2[cc];
            #pragma unroll
            for (int j = 0; j < 64; ++j) acc = fmaf(hb[512 + rr * 64 + j], Wd2[j * 24 + cc], acc);
            out[(r0 + rr) * 24 + cc] = acc;
        }
    }
}

extern "C" void kernel_launch(void* const* d_in, const int* in_sizes, int n_in,
                              void* d_out, int out_size, void* d_ws, size_t ws_size,
                              hipStream_t stream) {
    const float* x   = (const float*)d_in[0];
    const float* W1  = (const float*)d_in[1];
    const float* U1  = (const float*)d_in[2];
    const float* b1  = (const float*)d_in[3];
    const float* W2  = (const float*)d_in[4];
    const float* U2  = (const float*)d_in[5];
    const float* b2  = (const float*)d_in[6];
    // d_in[7..10] = Wq, bq, Wk, bk — dead: softmax over a length-1 axis is identically 1
    const float* Wv  = (const float*)d_in[11];
    const float* bv  = (const float*)d_in[12];
    const float* Wo  = (const float*)d_in[13];
    const float* bo  = (const float*)d_in[14];
    const float* Wd1 = (const float*)d_in[15];
    const float* bd1 = (const float*)d_in[16];
    const float* Wd2 = (const float*)d_in[17];
    const float* bd2 = (const float*)d_in[18];
    float* outp = (float*)d_out;

    hipLaunchKernelGGL(lstm_fused, dim3(B_TOTAL / RROWS), dim3(NT), 0, stream,
                       x, W1, U1, b1, W2, U2, b2, Wv, bv, Wo, bo,
                       Wd1, bd1, Wd2, bd2, outp);
}